// Round 5
// baseline (290.867 us; speedup 1.0000x reference)
//
#include <hip/hip_runtime.h>
#include <math.h>

#define HW    50176                // 224*224
#define BATCH 128
#define NUM_CLASSES 1000
#define TPB   256
#define TILE_PX        1024        // pixels staged per block
#define CHUNKS_PER_IMG 49          // 49 * 1024 = 50176 exactly
#define NBLOCKS (BATCH * CHUNKS_PER_IMG)   // 6272
#define NSTREAMS 10                // objects, gt0..gt4, locs0..locs3

typedef float v4f __attribute__((ext_vector_type(4)));

// ws layout (floats): ws[0] = pixel loss sum, ws[1] = class loss sum

__device__ __forceinline__ void load_lds16(const float* g, void* l) {
    // global -> LDS DMA, 16 B per lane. LDS dest = wave-uniform base + lane*16.
    // No destination VGPRs -> compiler cannot throttle outstanding loads.
    __builtin_amdgcn_global_load_lds(
        (const __attribute__((address_space(1))) void*)g,
        (__attribute__((address_space(3))) void*)l, 16, 0, 0);
}

__launch_bounds__(TPB, 2)
__global__ void pixel_loss_kernel(const float* __restrict__ objects,
                                  const float* __restrict__ locs,
                                  const float* __restrict__ gt,
                                  const float* __restrict__ obj_coor_p,
                                  const float* __restrict__ no_obj_confi_p,
                                  float* __restrict__ ws) {
    // 10 streams x 1024 floats x 4 B = 40,960 B -> exactly 4 blocks/CU (160 KiB)
    __shared__ v4f lds4[NSTREAMS * (TILE_PX / 4)];
    char* lds = (char*)lds4;

    const float coorW = *obj_coor_p;
    const float noW   = *no_obj_confi_p;

    const unsigned b    = blockIdx.x / CHUNKS_PER_IMG;
    const unsigned j    = blockIdx.x - b * CHUNKS_PER_IMG;
    const unsigned pix0 = j * TILE_PX;

    const unsigned lane = threadIdx.x & 63;
    const unsigned wave = threadIdx.x >> 6;   // 0..3

    // global bases (float offsets) for this tile
    const float* g0 = objects + b * HW + pix0;                 // objects
    const float* gg = gt   + (unsigned)(b * 5 * HW) + pix0;    // gt ch c: + c*HW
    const float* gl = locs + (unsigned)(b * 4 * HW) + pix0;    // locs ch c: + c*HW

    // ---- stage: wave w DMAs part w (1 KB) of every stream; 40 ops/block,
    //      all in flight simultaneously, zero VGPR destinations ----
    const unsigned fo = wave * 256 + lane * 4;   // float offset within stream chunk
    char* lbase = lds + wave * 1024;

    load_lds16(g0 + fo, lbase + 0 * 4096);
#pragma unroll
    for (int c = 0; c < 5; ++c)
        load_lds16(gg + c * HW + fo, lbase + (1 + c) * 4096);
#pragma unroll
    for (int c = 0; c < 4; ++c)
        load_lds16(gl + c * HW + fo, lbase + (6 + c) * 4096);

    __syncthreads();   // drains vmcnt -> all 40 KB resident in LDS

    // ---- compute: one float4-group (4 pixels) per thread, ds_read_b128,
    //      lane-consecutive addresses (conflict-free) ----
    const unsigned t = threadIdx.x;              // group 0..255
    v4f o  = lds4[0 * 256 + t];                  // objects
    v4f m4 = lds4[1 * 256 + t];                  // gt ch 0 (mask)
    v4f sq = {0.f, 0.f, 0.f, 0.f};
#pragma unroll
    for (int c = 0; c < 4; ++c) {
        v4f d = lds4[(6 + c) * 256 + t] - lds4[(2 + c) * 256 + t];
        sq += d * d;
    }

    float acc = 0.0f;
#pragma unroll
    for (int k = 0; k < 4; ++k) {
        const float p = o[k];
        const float m = m4[k];                   // exactly 0.0f or 1.0f
        const float lognop = fmaxf(__logf(1.0f - p), -100.0f);
        const float logp   = fmaxf(__logf(p), -100.0f);
        const float a  = -noW * lognop;                // m==0 contribution
        const float bb = fmaf(coorW, sq[k], -logp);    // m==1 contribution
        acc += fmaf(m, bb - a, a);                     // a + m*(b-a)
    }

    // ---- reduce: wave shuffle, then cross-wave via (reused) LDS ----
#pragma unroll
    for (int off = 32; off > 0; off >>= 1)
        acc += __shfl_down(acc, off, 64);

    __syncthreads();                // all LDS reads done before overwrite
    float* lr = (float*)lds;
    if (lane == 0) lr[wave] = acc;
    __syncthreads();
    if (threadIdx.x == 0)
        atomicAdd(&ws[0], lr[0] + lr[1] + lr[2] + lr[3]);
}

__global__ void class_loss_kernel(const float* __restrict__ scores,
                                  const int* __restrict__ label,
                                  float* __restrict__ ws) {
    const int b = blockIdx.x;
    const float* row = scores + b * NUM_CLASSES;

    __shared__ float red[4];
    __shared__ float s_bcast;
    const int lane = threadIdx.x & 63;
    const int wave = threadIdx.x >> 6;

    // --- max reduce ---
    float mx = -INFINITY;
    for (int i = threadIdx.x; i < NUM_CLASSES; i += blockDim.x)
        mx = fmaxf(mx, row[i]);
#pragma unroll
    for (int off = 32; off > 0; off >>= 1)
        mx = fmaxf(mx, __shfl_down(mx, off, 64));
    if (lane == 0) red[wave] = mx;
    __syncthreads();
    if (threadIdx.x == 0)
        s_bcast = fmaxf(fmaxf(red[0], red[1]), fmaxf(red[2], red[3]));
    __syncthreads();
    mx = s_bcast;

    // --- sum(exp) reduce ---
    float se = 0.0f;
    for (int i = threadIdx.x; i < NUM_CLASSES; i += blockDim.x)
        se += __expf(row[i] - mx);
#pragma unroll
    for (int off = 32; off > 0; off >>= 1)
        se += __shfl_down(se, off, 64);
    __syncthreads();   // protect red[] reuse
    if (lane == 0) red[wave] = se;
    __syncthreads();
    if (threadIdx.x == 0) {
        float lse = mx + logf(red[0] + red[1] + red[2] + red[3]);
        atomicAdd(&ws[1], -(row[label[b]] - lse));
    }
}

__global__ void finalize_kernel(const float* __restrict__ ws,
                                const float* __restrict__ img_class_weight_p,
                                float* __restrict__ out) {
    if (threadIdx.x == 0 && blockIdx.x == 0) {
        float img_class_loss = ws[1] / (float)BATCH;
        out[0] = img_class_weight_p[0] * img_class_loss + ws[0] / (float)BATCH;
    }
}

extern "C" void kernel_launch(void* const* d_in, const int* in_sizes, int n_in,
                              void* d_out, int out_size, void* d_ws, size_t ws_size,
                              hipStream_t stream) {
    const float* objects = (const float*)d_in[0];   // (B,H,W)
    const float* scores  = (const float*)d_in[1];   // (B,1000)
    const float* locs    = (const float*)d_in[2];   // (B,4,H,W)
    const int*   label   = (const int*)d_in[3];     // (B,)
    const float* gt      = (const float*)d_in[4];   // (B,5,H,W)
    const float* obj_coor         = (const float*)d_in[5];
    const float* no_obj_confi     = (const float*)d_in[6];
    const float* img_class_weight = (const float*)d_in[7];

    float* ws  = (float*)d_ws;
    float* out = (float*)d_out;

    hipMemsetAsync(ws, 0, 2 * sizeof(float), stream);

    pixel_loss_kernel<<<NBLOCKS, TPB, 0, stream>>>(
        objects, locs, gt, obj_coor, no_obj_confi, ws);

    class_loss_kernel<<<BATCH, 256, 0, stream>>>(scores, label, ws);

    finalize_kernel<<<1, 64, 0, stream>>>(ws, img_class_weight, out);
}